// Round 7
// baseline (349.910 us; speedup 1.0000x reference)
//
#include <hip/hip_runtime.h>

typedef __bf16 bf16;
typedef bf16 bf16x8 __attribute__((ext_vector_type(8)));
typedef float f32x4 __attribute__((ext_vector_type(4)));

#define TPB 256
#define UPAD 136   // u-scratch row stride in ushorts

__device__ inline unsigned short f2bf(float f){
  union{ bf16 h; unsigned short u; } v; v.h = (bf16)f; return v.u;
}
__device__ inline float bf2f(unsigned short u){
  union{ unsigned short u; bf16 h; } v; v.u = u; return (float)v.h;
}
__device__ inline unsigned int pk2(float a, float b){
  return (unsigned int)f2bf(a) | ((unsigned int)f2bf(b) << 16);
}
union BF8 { bf16x8 v; unsigned int u[4]; };
__device__ inline bf16x8 pack8(float4 a, float4 b){
  BF8 r; r.u[0] = pk2(a.x, a.y); r.u[1] = pk2(a.z, a.w);
  r.u[2] = pk2(b.x, b.y); r.u[3] = pk2(b.z, b.w); return r.v;
}

// ---- async weight staging: issue loads early (regs), ds_write late ----
struct StW { uint4 v[8]; };
__device__ inline StW wload(const unsigned short* __restrict__ src, int tid){
  StW w;
#pragma unroll
  for (int i = 0; i < 8; ++i){
    int p = tid + i*TPB;
    w.v[i] = *(const uint4*)(src + p*8);
  }
  return w;
}
__device__ inline void wwrite(unsigned short* dst, const StW& w, int tid){
#pragma unroll
  for (int i = 0; i < 8; ++i){
    int p = tid + i*TPB;
    *(uint4*)(dst + p*8) = w.v[i];
  }
}

// 2 K-chunks (128 K) of MFMA for a 16x128 wave tile; B from LDS wbuf (frags 0..31)
__device__ inline void gemm_lds2(const bf16x8* a, const unsigned short* wbuf,
                                 f32x4 acc[8], int lane){
#pragma unroll
  for (int cl = 0; cl < 2; ++cl)
#pragma unroll
    for (int kk = 0; kk < 2; ++kk){
      bf16x8 av = a[cl*2 + kk];
#pragma unroll
      for (int n = 0; n < 8; ++n){
        bf16x8 bv = *(const bf16x8*)(wbuf + (size_t)(((cl*8 + n)*2 + kk)*512) + lane*8);
        acc[n] = __builtin_amdgcn_mfma_f32_16x16x32_bf16(av, bv, acc[n], 0, 0, 0);
      }
    }
}

// per-row LN stats, in-wave (rows = lg*4+ri, cols = n*16+il)
__device__ inline void rowstats(const f32x4 acc[8], const float bia[8],
                                float mean[4], float rstd[4]){
#pragma unroll
  for (int ri = 0; ri < 4; ++ri){
    float s = 0.f, q = 0.f;
#pragma unroll
    for (int n = 0; n < 8; ++n){
      float z = acc[n][ri] + bia[n];
      s += z; q += z*z;
    }
#pragma unroll
    for (int m = 1; m < 16; m <<= 1){ s += __shfl_xor(s, m); q += __shfl_xor(q, m); }
    mean[ri] = s * (1.f/128.f);
    float var = q * (1.f/128.f) - mean[ri]*mean[ri];
    rstd[ri] = rsqrtf(var + 1e-5f);
  }
}

// =======================  kernels  =======================

// CSR-binned segment mean (verified R3-R6)
__global__ __launch_bounds__(TPB) void k_pool(const float* __restrict__ fine,
                                              const int* __restrict__ idx,
                                              unsigned short* __restrict__ pooled){
  int b = blockIdx.x >> 6, g = blockIdx.x & 63;
  int c0 = g * 8;
  __shared__ int sidx[4096];
  __shared__ int rows[512];
  __shared__ int cnt[8], off[9], woff[8];
  int tid = threadIdx.x;
  const int* idx_b = idx + b*4096;
  for (int i = tid; i < 4096; i += TPB) sidx[i] = idx_b[i];
  if (tid < 8) cnt[tid] = 0;
  __syncthreads();
  for (int i = tid; i < 4096; i += TPB){
    unsigned d = (unsigned)(sidx[i] - c0);
    if (d < 8u) atomicAdd(&cnt[d], 1);
  }
  __syncthreads();
  if (tid == 0){
    int s = 0;
#pragma unroll
    for (int j = 0; j < 8; ++j){ off[j] = s; s += cnt[j]; }
    off[8] = s;
  }
  __syncthreads();
  if (tid < 8) woff[tid] = off[tid];
  __syncthreads();
  for (int i = tid; i < 4096; i += TPB){
    unsigned d = (unsigned)(sidx[i] - c0);
    if (d < 8u){ int p = atomicAdd(&woff[d], 1); if (p < 512) rows[p] = i; }
  }
  __syncthreads();
  int hw = tid >> 5, l32 = tid & 31;
  const float* fb = fine + (size_t)b*4096*128;
  int o0 = off[hw], o1 = off[hw+1];
  float4 s = {0.f, 0.f, 0.f, 0.f};
  for (int m = o0; m < o1; ++m){
    float4 v = *((const float4*)(fb + (size_t)rows[m]*128) + l32);
    s.x += v.x; s.y += v.y; s.z += v.z; s.w += v.w;
  }
  float inv = 1.f / fmaxf((float)(o1 - o0), 1.f);
  unsigned short* po = pooled + ((size_t)(b*512 + c0 + hw))*128 + l32*4;
  po[0] = f2bf(s.x*inv); po[1] = f2bf(s.y*inv);
  po[2] = f2bf(s.z*inv); po[3] = f2bf(s.w*inv);
}

// W [K][128] fp32 -> B-fragment-ordered bf16 (frag=(c*8+nblk)*2+kk; 512 ushorts/frag)
__global__ __launch_bounds__(TPB) void k_prep(const float* __restrict__ Wp, const float* __restrict__ Wu,
                       const float* __restrict__ Wg, const float* __restrict__ Wgl,
                       unsigned short* __restrict__ WfP, unsigned short* __restrict__ WfU,
                       unsigned short* __restrict__ WfG, unsigned short* __restrict__ WfGl){
  int e = blockIdx.x * TPB + threadIdx.x;      // 0..32767
  int j = e & 7, lane = (e >> 3) & 63, frag = e >> 9;
  int kk = frag & 1, nblk = (frag >> 1) & 7, c = frag >> 4;
  int il = lane & 15, lg = lane >> 4;
  int col = nblk*16 + il;
  int k = c*64 + kk*32 + lg*8 + j;
  if (e < 16384){
    WfP[e] = f2bf(Wp[k*128 + col]);
    WfU[e] = f2bf(Wu[k*128 + col]);
  }
  WfG[e]  = f2bf(Wg[k*128 + col]);
  WfGl[e] = f2bf(Wgl[k*128 + col]);
}

// Fused pipeline: 4 waves/block, each wave an independent 16x128 tile.
// Weights staged through a 32KB LDS window in 5 phases, ASYNC (load-early/write-late).
// PATH 0 additionally accumulates the per-batch glob mean into gmean (used by PATH 1).
template<int PATH>   // 0 = fine path, 1 = coarse path
__global__ __launch_bounds__(TPB, 3) void k_mega(
    const float* __restrict__ a_src,
    const float* __restrict__ gath_src,
    const unsigned short* __restrict__ x1b,
    const int* __restrict__ idx,
    const float* __restrict__ gsrc,
    float gscale,
    const unsigned short* __restrict__ Wf1, const float* __restrict__ b1,
    const float* __restrict__ g1, const float* __restrict__ be1,
    const unsigned short* __restrict__ WfG, const float* __restrict__ bG,
    const unsigned short* __restrict__ WfGl, const float* __restrict__ bGl,
    const float* __restrict__ gGl, const float* __restrict__ beGl,
    float* __restrict__ gmean_out,
    float* __restrict__ out)
{
  __shared__ unsigned short wbuf[16384];       // 32 KB weight phase window
  __shared__ unsigned short ubuf[4][16*UPAD];  // 17.4 KB per-wave u scratch
  int tid = threadIdx.x;
  int wave = tid >> 6, lane = tid & 63;
  int il = lane & 15, lg = lane >> 4;
  int row0 = blockIdx.x * 64 + wave * 16;
  int b = (PATH == 0) ? (row0 >> 12) : (row0 >> 9);
  unsigned short* u = ubuf[wave];

  // ===== prologue: A1 loads + W1 stage (latency unavoidable once) =====
  bf16x8 a1[4];
  if (PATH == 0){
    int n0 = row0 & 4095;
    int ci = idx[b*4096 + n0 + il];
    bool valid = (unsigned)ci < 512u;
    const float* cr = gath_src + ((size_t)b*512 + (valid ? ci : 0))*128;
#pragma unroll
    for (int c = 0; c < 2; ++c)
#pragma unroll
      for (int kk = 0; kk < 2; ++kk){
        float4 f0 = {0.f,0.f,0.f,0.f}, f1 = {0.f,0.f,0.f,0.f};
        if (valid){
          f0 = *(const float4*)(cr + c*64 + kk*32 + lg*8);
          f1 = *(const float4*)(cr + c*64 + kk*32 + lg*8 + 4);
        }
        a1[c*2 + kk] = pack8(f0, f1);
      }
  } else {
    const unsigned short* pr = x1b + (size_t)(row0 + il)*128;
#pragma unroll
    for (int c = 0; c < 2; ++c)
#pragma unroll
      for (int kk = 0; kk < 2; ++kk)
        a1[c*2 + kk] = *(const bf16x8*)(pr + c*64 + kk*32 + lg*8);
  }
  {
    StW w1 = wload(Wf1, tid);
    wwrite(wbuf, w1, tid);
  }
  StW wnext = wload(WfG, tid);                  // issue WG-lo early
  __syncthreads();                              // W1 ready

  f32x4 acc[8] = {};
  gemm_lds2(a1, wbuf, acc, lane);
  {
    float bia[8], gmv[8], btv[8];
#pragma unroll
    for (int n = 0; n < 8; ++n){
      int col = n*16 + il;
      bia[n] = b1[col]; gmv[n] = g1[col]; btv[n] = be1[col];
    }
    float mean[4], rstd[4];
    rowstats(acc, bia, mean, rstd);
#pragma unroll
    for (int ri = 0; ri < 4; ++ri)
#pragma unroll
      for (int n = 0; n < 8; ++n){
        float z = acc[n][ri] + bia[n];
        float y = fmaxf((z - mean[ri])*rstd[ri]*gmv[n] + btv[n], 0.f);
        u[(lg*4 + ri)*UPAD + n*16 + il] = f2bf(y);
      }
  }

  // issue GEMM2 global-A loads (consumed 2 barriers later)
  const float* ar = a_src + (size_t)(row0 + il)*128;
  float4 raw[8];
#pragma unroll
  for (int c = 0; c < 2; ++c)
#pragma unroll
    for (int kk = 0; kk < 2; ++kk){
      raw[(c*2+kk)*2+0] = *(const float4*)(ar + c*64 + kk*32 + lg*8);
      raw[(c*2+kk)*2+1] = *(const float4*)(ar + c*64 + kk*32 + lg*8 + 4);
    }

  __syncthreads();                              // all done reading W1
  wwrite(wbuf, wnext, tid);                     // WG-lo (loads long in flight)
  wnext = wload(WfG + 16384, tid);              // issue WG-hi
  __syncthreads();                              // WG-lo ready

  // ===== GEMM2 (gate): chunks 0,1 from global A =====
#pragma unroll
  for (int n = 0; n < 8; ++n) acc[n] = (f32x4){0.f,0.f,0.f,0.f};
  bf16x8 af[4];
#pragma unroll
  for (int f = 0; f < 4; ++f) af[f] = pack8(raw[f*2], raw[f*2+1]);
  gemm_lds2(af, wbuf, acc, lane);

  __syncthreads();                              // done reading WG-lo
  wwrite(wbuf, wnext, tid);                     // WG-hi
  wnext = wload(WfGl, tid);                     // issue WGl-lo
  __syncthreads();                              // WG-hi ready

  // chunks 2,3 from u1
#pragma unroll
  for (int cl = 0; cl < 2; ++cl)
#pragma unroll
    for (int kk = 0; kk < 2; ++kk)
      af[cl*2 + kk] = *(const bf16x8*)(u + il*UPAD + cl*64 + kk*32 + lg*8);
  gemm_lds2(af, wbuf, acc, lane);

  // gate epilogue: u2 = g*a + (1-g)*u1  (per-lane RMW on own u addresses)
#pragma unroll
  for (int ri = 0; ri < 4; ++ri){
    int grow = (row0 + lg*4 + ri)*128;
#pragma unroll
    for (int n = 0; n < 8; ++n){
      int col = n*16 + il;
      float z = acc[n][ri] + bG[col];
      float gt = 1.f / (1.f + __expf(-z));
      float f  = a_src[(size_t)grow + col];
      int ua = (lg*4 + ri)*UPAD + col;
      float u1 = bf2f(u[ua]);
      u[ua] = f2bf(gt*f + (1.f - gt)*u1);
    }
  }

  // issue GEMM3 global-A loads (glob rows | gmean broadcast)
  if (PATH == 0){
    const float* gr = gsrc + (size_t)(row0 + il)*128;
#pragma unroll
    for (int c = 0; c < 2; ++c)
#pragma unroll
      for (int kk = 0; kk < 2; ++kk){
        raw[(c*2+kk)*2+0] = *(const float4*)(gr + c*64 + kk*32 + lg*8);
        raw[(c*2+kk)*2+1] = *(const float4*)(gr + c*64 + kk*32 + lg*8 + 4);
      }
    // fused per-batch glob mean: reduce the 16 rows across il-lanes, atomics from il==0
    float4 ps[8];
#pragma unroll
    for (int f = 0; f < 8; ++f) ps[f] = raw[f];
#pragma unroll
    for (int m = 1; m < 16; m <<= 1)
#pragma unroll
      for (int f = 0; f < 8; ++f){
        ps[f].x += __shfl_xor(ps[f].x, m);
        ps[f].y += __shfl_xor(ps[f].y, m);
        ps[f].z += __shfl_xor(ps[f].z, m);
        ps[f].w += __shfl_xor(ps[f].w, m);
      }
    if (il == 0){
      float* gm = gmean_out + b*128;
#pragma unroll
      for (int f = 0; f < 8; ++f){
        int c = (f>>2)*64 + ((f>>1)&1)*32 + lg*8 + (f&1)*4;
        atomicAdd(&gm[c+0], ps[f].x);
        atomicAdd(&gm[c+1], ps[f].y);
        atomicAdd(&gm[c+2], ps[f].z);
        atomicAdd(&gm[c+3], ps[f].w);
      }
    }
  } else {
    const float* gm = gsrc + b*128;
#pragma unroll
    for (int c = 0; c < 2; ++c)
#pragma unroll
      for (int kk = 0; kk < 2; ++kk){
        float4 f0 = *(const float4*)(gm + c*64 + kk*32 + lg*8);
        float4 f1 = *(const float4*)(gm + c*64 + kk*32 + lg*8 + 4);
        raw[(c*2+kk)*2+0] = (float4){f0.x*gscale, f0.y*gscale, f0.z*gscale, f0.w*gscale};
        raw[(c*2+kk)*2+1] = (float4){f1.x*gscale, f1.y*gscale, f1.z*gscale, f1.w*gscale};
      }
  }

  __syncthreads();                              // done reading WG-hi
  wwrite(wbuf, wnext, tid);                     // WGl-lo
  wnext = wload(WfGl + 16384, tid);             // issue WGl-hi
  __syncthreads();                              // WGl-lo ready

  // ===== GEMM3 (glob): chunks 0,1 from u2 =====
#pragma unroll
  for (int n = 0; n < 8; ++n) acc[n] = (f32x4){0.f,0.f,0.f,0.f};
#pragma unroll
  for (int cl = 0; cl < 2; ++cl)
#pragma unroll
    for (int kk = 0; kk < 2; ++kk)
      af[cl*2 + kk] = *(const bf16x8*)(u + il*UPAD + cl*64 + kk*32 + lg*8);
  gemm_lds2(af, wbuf, acc, lane);

  __syncthreads();                              // done reading WGl-lo
  wwrite(wbuf, wnext, tid);                     // WGl-hi
  __syncthreads();                              // ready
#pragma unroll
  for (int f = 0; f < 4; ++f) af[f] = pack8(raw[f*2], raw[f*2+1]);
  gemm_lds2(af, wbuf, acc, lane);

  // final LN + residual
  {
    float bia[8], gmv[8], btv[8];
#pragma unroll
    for (int n = 0; n < 8; ++n){
      int col = n*16 + il;
      bia[n] = bGl[col]; gmv[n] = gGl[col]; btv[n] = beGl[col];
    }
    float mean[4], rstd[4];
    rowstats(acc, bia, mean, rstd);
#pragma unroll
    for (int ri = 0; ri < 4; ++ri){
      int grow = (row0 + lg*4 + ri)*128;
#pragma unroll
      for (int n = 0; n < 8; ++n){
        int col = n*16 + il;
        float z = acc[n][ri] + bia[n];
        float y = fmaxf((z - mean[ri])*rstd[ri]*gmv[n] + btv[n], 0.f);
        float u2 = bf2f(u[(lg*4 + ri)*UPAD + col]);
        out[(size_t)grow + col] = u2 + 0.1f*y;
      }
    }
  }
}

extern "C" void kernel_launch(void* const* d_in, const int* in_sizes, int n_in,
                              void* d_out, int out_size, void* d_ws, size_t ws_size,
                              hipStream_t stream){
  const float* fine    = (const float*)d_in[0];
  const float* coarse  = (const float*)d_in[1];
  const float* glob    = (const float*)d_in[2];
  const int*   idx     = (const int*)  d_in[3];
  const float* W_pool  = (const float*)d_in[4];
  const float* b_pool  = (const float*)d_in[5];
  const float* g_pool  = (const float*)d_in[6];
  const float* be_pool = (const float*)d_in[7];
  const float* W_unpool  = (const float*)d_in[8];
  const float* b_unpool  = (const float*)d_in[9];
  const float* g_unpool  = (const float*)d_in[10];
  const float* be_unpool = (const float*)d_in[11];
  const float* W_gate = (const float*)d_in[12];
  const float* b_gate = (const float*)d_in[13];
  const float* W_glob = (const float*)d_in[14];
  const float* b_glob = (const float*)d_in[15];
  const float* g_glob = (const float*)d_in[16];
  const float* be_glob= (const float*)d_in[17];

  const int B = 32, N = 4096, C = 512;
  float* out_fine   = (float*)d_out;
  float* out_coarse = out_fine + (size_t)B*N*128;

  char* w = (char*)d_ws;
  unsigned short* WfP  = (unsigned short*)w; w += 16384*2;
  unsigned short* WfU  = (unsigned short*)w; w += 16384*2;
  unsigned short* WfG  = (unsigned short*)w; w += 32768*2;
  unsigned short* WfGl = (unsigned short*)w; w += 32768*2;
  float* gmean = (float*)w;                  w += B*128*4;
  unsigned short* pooled = (unsigned short*)w; w += (size_t)B*C*128*2;

  hipMemsetAsync(gmean, 0, B*128*4, stream);
  k_prep<<<128, TPB, 0, stream>>>(W_pool, W_unpool, W_gate, W_glob, WfP, WfU, WfG, WfGl);
  k_pool<<<B*64, TPB, 0, stream>>>(fine, idx, pooled);

  // fine path: unpool(gather) -> gate -> glob (+ gmean accumulation)
  k_mega<0><<<(B*N)/64, TPB, 0, stream>>>(fine, coarse, nullptr, idx, glob, 1.0f,
                                          WfU, b_unpool, g_unpool, be_unpool,
                                          WfG, b_gate, WfGl, b_glob, g_glob, be_glob,
                                          gmean, out_fine);
  // coarse path: pool-block -> gate -> glob (consumes gmean)
  k_mega<1><<<(B*C)/64, TPB, 0, stream>>>(coarse, nullptr, pooled, nullptr, gmean, 1.f/4096.f,
                                          WfP, b_pool, g_pool, be_pool,
                                          WfG, b_gate, WfGl, b_glob, g_glob, be_glob,
                                          nullptr, out_coarse);
}

// Round 8
// 251.576 us; speedup vs baseline: 1.3909x; 1.3909x over previous
//
#include <hip/hip_runtime.h>

typedef __bf16 bf16;
typedef bf16 bf16x8 __attribute__((ext_vector_type(8)));
typedef float f32x4 __attribute__((ext_vector_type(4)));

#define TPB 256
#define UPAD 136   // u-scratch row stride in ushorts (272B = 17*16B)

__device__ inline unsigned short f2bf(float f){
  union{ bf16 h; unsigned short u; } v; v.h = (bf16)f; return v.u;
}
__device__ inline float bf2f(unsigned short u){
  union{ unsigned short u; bf16 h; } v; v.u = u; return (float)v.h;
}
__device__ inline unsigned int pk2(float a, float b){
  return (unsigned int)f2bf(a) | ((unsigned int)f2bf(b) << 16);
}
union BF8 { bf16x8 v; unsigned int u[4]; };
__device__ inline bf16x8 pack8(float4 a, float4 b){
  BF8 r; r.u[0] = pk2(a.x, a.y); r.u[1] = pk2(a.z, a.w);
  r.u[2] = pk2(b.x, b.y); r.u[3] = pk2(b.z, b.w); return r.v;
}

// ---- async global->LDS weight staging (zero VGPRs, drained by __syncthreads) ----
__device__ inline void gll16(const unsigned short* g, unsigned short* l){
  __builtin_amdgcn_global_load_lds(
      (const __attribute__((address_space(1))) unsigned int*)g,
      (__attribute__((address_space(3))) unsigned int*)l, 16, 0, 0);
}
// one 16KB chunk (16 frags of 512 ushorts): 4 x (256 lanes x 16B)
__device__ inline void stage16k(const unsigned short* __restrict__ src,
                                unsigned short* dst, int tid){
#pragma unroll
  for (int i = 0; i < 4; ++i){
    int p = (tid + i*TPB)*8;
    gll16(src + p, dst + p);
  }
}

// one 64-K chunk of MFMA for a 16x128 wave tile; B from a 16KB LDS window
__device__ inline void gemm_lds1(const bf16x8* a, const unsigned short* wbuf,
                                 f32x4 acc[8], int lane){
#pragma unroll
  for (int kk = 0; kk < 2; ++kk){
    bf16x8 av = a[kk];
#pragma unroll
    for (int n = 0; n < 8; ++n){
      bf16x8 bv = *(const bf16x8*)(wbuf + (size_t)((n*2 + kk)*512) + lane*8);
      acc[n] = __builtin_amdgcn_mfma_f32_16x16x32_bf16(av, bv, acc[n], 0, 0, 0);
    }
  }
}

// per-row LN stats, in-wave (rows = lg*4+ri, cols = n*16+il)
__device__ inline void rowstats(const f32x4 acc[8], const float bia[8],
                                float mean[4], float rstd[4]){
#pragma unroll
  for (int ri = 0; ri < 4; ++ri){
    float s = 0.f, q = 0.f;
#pragma unroll
    for (int n = 0; n < 8; ++n){
      float z = acc[n][ri] + bia[n];
      s += z; q += z*z;
    }
#pragma unroll
    for (int m = 1; m < 16; m <<= 1){ s += __shfl_xor(s, m); q += __shfl_xor(q, m); }
    mean[ri] = s * (1.f/128.f);
    float var = q * (1.f/128.f) - mean[ri]*mean[ri];
    rstd[ri] = rsqrtf(var + 1e-5f);
  }
}

// =======================  kernels  =======================

// CSR-binned segment mean (verified R3-R7)
__global__ __launch_bounds__(TPB) void k_pool(const float* __restrict__ fine,
                                              const int* __restrict__ idx,
                                              unsigned short* __restrict__ pooled){
  int b = blockIdx.x >> 6, g = blockIdx.x & 63;
  int c0 = g * 8;
  __shared__ int sidx[4096];
  __shared__ int rows[512];
  __shared__ int cnt[8], off[9], woff[8];
  int tid = threadIdx.x;
  const int* idx_b = idx + b*4096;
  for (int i = tid; i < 4096; i += TPB) sidx[i] = idx_b[i];
  if (tid < 8) cnt[tid] = 0;
  __syncthreads();
  for (int i = tid; i < 4096; i += TPB){
    unsigned d = (unsigned)(sidx[i] - c0);
    if (d < 8u) atomicAdd(&cnt[d], 1);
  }
  __syncthreads();
  if (tid == 0){
    int s = 0;
#pragma unroll
    for (int j = 0; j < 8; ++j){ off[j] = s; s += cnt[j]; }
    off[8] = s;
  }
  __syncthreads();
  if (tid < 8) woff[tid] = off[tid];
  __syncthreads();
  for (int i = tid; i < 4096; i += TPB){
    unsigned d = (unsigned)(sidx[i] - c0);
    if (d < 8u){ int p = atomicAdd(&woff[d], 1); if (p < 512) rows[p] = i; }
  }
  __syncthreads();
  int hw = tid >> 5, l32 = tid & 31;
  const float* fb = fine + (size_t)b*4096*128;
  int o0 = off[hw], o1 = off[hw+1];
  float4 s = {0.f, 0.f, 0.f, 0.f};
  for (int m = o0; m < o1; ++m){
    float4 v = *((const float4*)(fb + (size_t)rows[m]*128) + l32);
    s.x += v.x; s.y += v.y; s.z += v.z; s.w += v.w;
  }
  float inv = 1.f / fmaxf((float)(o1 - o0), 1.f);
  unsigned short* po = pooled + ((size_t)(b*512 + c0 + hw))*128 + l32*4;
  po[0] = f2bf(s.x*inv); po[1] = f2bf(s.y*inv);
  po[2] = f2bf(s.z*inv); po[3] = f2bf(s.w*inv);
}

// W [K][128] fp32 -> B-fragment-ordered bf16 (frag=(c*8+nblk)*2+kk; 512 ushorts/frag)
__global__ __launch_bounds__(TPB) void k_prep(const float* __restrict__ Wp, const float* __restrict__ Wu,
                       const float* __restrict__ Wg, const float* __restrict__ Wgl,
                       unsigned short* __restrict__ WfP, unsigned short* __restrict__ WfU,
                       unsigned short* __restrict__ WfG, unsigned short* __restrict__ WfGl){
  int e = blockIdx.x * TPB + threadIdx.x;      // 0..32767
  int j = e & 7, lane = (e >> 3) & 63, frag = e >> 9;
  int kk = frag & 1, nblk = (frag >> 1) & 7, c = frag >> 4;
  int il = lane & 15, lg = lane >> 4;
  int col = nblk*16 + il;
  int k = c*64 + kk*32 + lg*8 + j;
  if (e < 16384){
    WfP[e] = f2bf(Wp[k*128 + col]);
    WfU[e] = f2bf(Wu[k*128 + col]);
  }
  WfG[e]  = f2bf(Wg[k*128 + col]);
  WfGl[e] = f2bf(Wgl[k*128 + col]);
}

// Fused pipeline: 4 waves/block, each wave an independent 16x128 tile.
// Weights DMA'd via global_load_lds through 2 x 16KB double-buffered windows (9 barriers).
// PATH 0 additionally accumulates the per-batch glob mean into gmean (used by PATH 1).
template<int PATH>   // 0 = fine path, 1 = coarse path
__global__ __launch_bounds__(TPB, 3) void k_mega(
    const float* __restrict__ a_src,
    const float* __restrict__ gath_src,
    const unsigned short* __restrict__ x1b,
    const int* __restrict__ idx,
    const float* __restrict__ gsrc,
    float gscale,
    const unsigned short* __restrict__ Wf1, const float* __restrict__ b1,
    const float* __restrict__ g1, const float* __restrict__ be1,
    const unsigned short* __restrict__ WfG, const float* __restrict__ bG,
    const unsigned short* __restrict__ WfGl, const float* __restrict__ bGl,
    const float* __restrict__ gGl, const float* __restrict__ beGl,
    float* __restrict__ gmean_out,
    float* __restrict__ out)
{
  __shared__ __align__(16) unsigned short wb[2][8192];      // 2 x 16 KB weight windows
  __shared__ __align__(16) unsigned short ubuf[4][16*UPAD]; // 17.4 KB per-wave u scratch
  int tid = threadIdx.x;
  int wave = tid >> 6, lane = tid & 63;
  int il = lane & 15, lg = lane >> 4;
  int row0 = blockIdx.x * 64 + wave * 16;
  int b = (PATH == 0) ? (row0 >> 12) : (row0 >> 9);
  unsigned short* u = ubuf[wave];

  // ===== prologue: stage W1 (both chunks) + A1 loads =====
  stage16k(Wf1,        wb[0], tid);
  stage16k(Wf1 + 8192, wb[1], tid);
  bf16x8 a1[4];
  if (PATH == 0){
    int n0 = row0 & 4095;
    int ci = idx[b*4096 + n0 + il];
    bool valid = (unsigned)ci < 512u;
    const float* cr = gath_src + ((size_t)b*512 + (valid ? ci : 0))*128;
#pragma unroll
    for (int c = 0; c < 2; ++c)
#pragma unroll
      for (int kk = 0; kk < 2; ++kk){
        float4 f0 = {0.f,0.f,0.f,0.f}, f1 = {0.f,0.f,0.f,0.f};
        if (valid){
          f0 = *(const float4*)(cr + c*64 + kk*32 + lg*8);
          f1 = *(const float4*)(cr + c*64 + kk*32 + lg*8 + 4);
        }
        a1[c*2 + kk] = pack8(f0, f1);
      }
  } else {
    const unsigned short* pr = x1b + (size_t)(row0 + il)*128;
#pragma unroll
    for (int c = 0; c < 2; ++c)
#pragma unroll
      for (int kk = 0; kk < 2; ++kk)
        a1[c*2 + kk] = *(const bf16x8*)(pr + c*64 + kk*32 + lg*8);
  }
  __syncthreads();                              // S1: W1 ready

  // ===== GEMM1 (K=128) =====
  f32x4 acc[8] = {};
  gemm_lds1(a1 + 0, wb[0], acc, lane);
  gemm_lds1(a1 + 2, wb[1], acc, lane);

  // prefetch GEMM2 A (a rows) while wbuf still busy elsewhere
  const float* ar = a_src + (size_t)(row0 + il)*128;
  float4 raw[8];
#pragma unroll
  for (int c = 0; c < 2; ++c)
#pragma unroll
    for (int kk = 0; kk < 2; ++kk){
      raw[(c*2+kk)*2+0] = *(const float4*)(ar + c*64 + kk*32 + lg*8);
      raw[(c*2+kk)*2+1] = *(const float4*)(ar + c*64 + kk*32 + lg*8 + 4);
    }
  __syncthreads();                              // S2: wb free
  stage16k(WfG,        wb[0], tid);             // WG chunks 0,1 (async)
  stage16k(WfG + 8192, wb[1], tid);

  // GEMM1 epilogue covers the staging
  {
    float bia[8], gmv[8], btv[8];
#pragma unroll
    for (int n = 0; n < 8; ++n){
      int col = n*16 + il;
      bia[n] = b1[col]; gmv[n] = g1[col]; btv[n] = be1[col];
    }
    float mean[4], rstd[4];
    rowstats(acc, bia, mean, rstd);
#pragma unroll
    for (int ri = 0; ri < 4; ++ri)
#pragma unroll
      for (int n = 0; n < 8; ++n){
        float z = acc[n][ri] + bia[n];
        float y = fmaxf((z - mean[ri])*rstd[ri]*gmv[n] + btv[n], 0.f);
        u[(lg*4 + ri)*UPAD + n*16 + il] = f2bf(y);
      }
  }
  bf16x8 af[4];
#pragma unroll
  for (int f = 0; f < 4; ++f) af[f] = pack8(raw[f*2], raw[f*2+1]);
  __syncthreads();                              // S3: WG01 ready

  // ===== GEMM2 (gate): chunks 0,1 from a =====
#pragma unroll
  for (int n = 0; n < 8; ++n) acc[n] = (f32x4){0.f,0.f,0.f,0.f};
  gemm_lds1(af + 0, wb[0], acc, lane);
  gemm_lds1(af + 2, wb[1], acc, lane);
  __syncthreads();                              // S4: wb free
  stage16k(WfG + 16384, wb[0], tid);            // WG chunks 2,3
  stage16k(WfG + 24576, wb[1], tid);
#pragma unroll
  for (int cl = 0; cl < 2; ++cl)                // u1 frags (per-wave LDS)
#pragma unroll
    for (int kk = 0; kk < 2; ++kk)
      af[cl*2 + kk] = *(const bf16x8*)(u + il*UPAD + cl*64 + kk*32 + lg*8);
  __syncthreads();                              // S5: WG23 ready
  gemm_lds1(af + 0, wb[0], acc, lane);
  gemm_lds1(af + 2, wb[1], acc, lane);

  // gate epilogue: u2 = g*a + (1-g)*u1 (per-lane RMW on own u addrs)
#pragma unroll
  for (int ri = 0; ri < 4; ++ri){
    int grow = (row0 + lg*4 + ri)*128;
#pragma unroll
    for (int n = 0; n < 8; ++n){
      int col = n*16 + il;
      float z = acc[n][ri] + bG[col];
      float gt = 1.f / (1.f + __expf(-z));
      float f  = a_src[(size_t)grow + col];
      int ua = (lg*4 + ri)*UPAD + col;
      float u1 = bf2f(u[ua]);
      u[ua] = f2bf(gt*f + (1.f - gt)*u1);
    }
  }

  // prefetch GEMM3 A (glob rows | gmean broadcast); PATH0 also reduces gmean
  if (PATH == 0){
    const float* gr = gsrc + (size_t)(row0 + il)*128;
#pragma unroll
    for (int c = 0; c < 2; ++c)
#pragma unroll
      for (int kk = 0; kk < 2; ++kk){
        raw[(c*2+kk)*2+0] = *(const float4*)(gr + c*64 + kk*32 + lg*8);
        raw[(c*2+kk)*2+1] = *(const float4*)(gr + c*64 + kk*32 + lg*8 + 4);
      }
    float* gm = gmean_out + b*128;
#pragma unroll
    for (int f = 0; f < 8; ++f){
      float4 p = raw[f];
#pragma unroll
      for (int m = 1; m < 16; m <<= 1){
        p.x += __shfl_xor(p.x, m); p.y += __shfl_xor(p.y, m);
        p.z += __shfl_xor(p.z, m); p.w += __shfl_xor(p.w, m);
      }
      if (il == 0){
        int c = (f>>2)*64 + ((f>>1)&1)*32 + lg*8 + (f&1)*4;
        atomicAdd(&gm[c+0], p.x); atomicAdd(&gm[c+1], p.y);
        atomicAdd(&gm[c+2], p.z); atomicAdd(&gm[c+3], p.w);
      }
    }
  } else {
    const float* gm = gsrc + b*128;
#pragma unroll
    for (int c = 0; c < 2; ++c)
#pragma unroll
      for (int kk = 0; kk < 2; ++kk){
        float4 f0 = *(const float4*)(gm + c*64 + kk*32 + lg*8);
        float4 f1 = *(const float4*)(gm + c*64 + kk*32 + lg*8 + 4);
        raw[(c*2+kk)*2+0] = (float4){f0.x*gscale, f0.y*gscale, f0.z*gscale, f0.w*gscale};
        raw[(c*2+kk)*2+1] = (float4){f1.x*gscale, f1.y*gscale, f1.z*gscale, f1.w*gscale};
      }
  }
  __syncthreads();                              // S6: wb free
  stage16k(WfGl,        wb[0], tid);            // WGl chunks 0,1
  stage16k(WfGl + 8192, wb[1], tid);
#pragma unroll
  for (int cl = 0; cl < 2; ++cl)                // u2 frags (per-wave LDS)
#pragma unroll
    for (int kk = 0; kk < 2; ++kk)
      af[cl*2 + kk] = *(const bf16x8*)(u + il*UPAD + cl*64 + kk*32 + lg*8);
  __syncthreads();                              // S7: WGl01 ready

  // ===== GEMM3 (glob): chunks 0,1 from u2 =====
#pragma unroll
  for (int n = 0; n < 8; ++n) acc[n] = (f32x4){0.f,0.f,0.f,0.f};
  gemm_lds1(af + 0, wb[0], acc, lane);
  gemm_lds1(af + 2, wb[1], acc, lane);
  __syncthreads();                              // S8: wb free
  stage16k(WfGl + 16384, wb[0], tid);           // WGl chunks 2,3
  stage16k(WfGl + 24576, wb[1], tid);
#pragma unroll
  for (int f = 0; f < 4; ++f) af[f] = pack8(raw[f*2], raw[f*2+1]);
  __syncthreads();                              // S9: ready
  gemm_lds1(af + 0, wb[0], acc, lane);
  gemm_lds1(af + 2, wb[1], acc, lane);

  // final LN + residual
  {
    float bia[8], gmv[8], btv[8];
#pragma unroll
    for (int n = 0; n < 8; ++n){
      int col = n*16 + il;
      bia[n] = bGl[col]; gmv[n] = gGl[col]; btv[n] = beGl[col];
    }
    float mean[4], rstd[4];
    rowstats(acc, bia, mean, rstd);
#pragma unroll
    for (int ri = 0; ri < 4; ++ri){
      int grow = (row0 + lg*4 + ri)*128;
#pragma unroll
      for (int n = 0; n < 8; ++n){
        int col = n*16 + il;
        float z = acc[n][ri] + bia[n];
        float y = fmaxf((z - mean[ri])*rstd[ri]*gmv[n] + btv[n], 0.f);
        float u2 = bf2f(u[(lg*4 + ri)*UPAD + col]);
        out[(size_t)grow + col] = u2 + 0.1f*y;
      }
    }
  }
}

extern "C" void kernel_launch(void* const* d_in, const int* in_sizes, int n_in,
                              void* d_out, int out_size, void* d_ws, size_t ws_size,
                              hipStream_t stream){
  const float* fine    = (const float*)d_in[0];
  const float* coarse  = (const float*)d_in[1];
  const float* glob    = (const float*)d_in[2];
  const int*   idx     = (const int*)  d_in[3];
  const float* W_pool  = (const float*)d_in[4];
  const float* b_pool  = (const float*)d_in[5];
  const float* g_pool  = (const float*)d_in[6];
  const float* be_pool = (const float*)d_in[7];
  const float* W_unpool  = (const float*)d_in[8];
  const float* b_unpool  = (const float*)d_in[9];
  const float* g_unpool  = (const float*)d_in[10];
  const float* be_unpool = (const float*)d_in[11];
  const float* W_gate = (const float*)d_in[12];
  const float* b_gate = (const float*)d_in[13];
  const float* W_glob = (const float*)d_in[14];
  const float* b_glob = (const float*)d_in[15];
  const float* g_glob = (const float*)d_in[16];
  const float* be_glob= (const float*)d_in[17];

  const int B = 32, N = 4096, C = 512;
  float* out_fine   = (float*)d_out;
  float* out_coarse = out_fine + (size_t)B*N*128;

  char* w = (char*)d_ws;
  unsigned short* WfP  = (unsigned short*)w; w += 16384*2;
  unsigned short* WfU  = (unsigned short*)w; w += 16384*2;
  unsigned short* WfG  = (unsigned short*)w; w += 32768*2;
  unsigned short* WfGl = (unsigned short*)w; w += 32768*2;
  float* gmean = (float*)w;                  w += B*128*4;
  unsigned short* pooled = (unsigned short*)w; w += (size_t)B*C*128*2;

  hipMemsetAsync(gmean, 0, B*128*4, stream);
  k_prep<<<128, TPB, 0, stream>>>(W_pool, W_unpool, W_gate, W_glob, WfP, WfU, WfG, WfGl);
  k_pool<<<B*64, TPB, 0, stream>>>(fine, idx, pooled);

  // fine path: unpool(gather) -> gate -> glob (+ gmean accumulation)
  k_mega<0><<<(B*N)/64, TPB, 0, stream>>>(fine, coarse, nullptr, idx, glob, 1.0f,
                                          WfU, b_unpool, g_unpool, be_unpool,
                                          WfG, b_gate, WfGl, b_glob, g_glob, be_glob,
                                          gmean, out_fine);
  // coarse path: pool-block -> gate -> glob (consumes gmean)
  k_mega<1><<<(B*C)/64, TPB, 0, stream>>>(coarse, nullptr, pooled, nullptr, gmean, 1.f/4096.f,
                                          WfP, b_pool, g_pool, be_pool,
                                          WfG, b_gate, WfGl, b_glob, g_glob, be_glob,
                                          nullptr, out_coarse);
}

// Round 9
// 124.928 us; speedup vs baseline: 2.8009x; 2.0138x over previous
//
#include <hip/hip_runtime.h>

typedef __bf16 bf16;
typedef bf16 bf16x8 __attribute__((ext_vector_type(8)));
typedef float f32x4 __attribute__((ext_vector_type(4)));

#define TPB 256    // pool/gmean/prep block size
#define TPM 512    // mega block size (8 waves, 128 rows)
#define UPAD 136   // u-scratch row stride in ushorts

__device__ inline unsigned short f2bf(float f){
  union{ bf16 h; unsigned short u; } v; v.h = (bf16)f; return v.u;
}
__device__ inline float bf2f(unsigned short u){
  union{ unsigned short u; bf16 h; } v; v.u = u; return (float)v.h;
}
__device__ inline unsigned int pk2(float a, float b){
  return (unsigned int)f2bf(a) | ((unsigned int)f2bf(b) << 16);
}
union BF8 { bf16x8 v; unsigned int u[4]; };
__device__ inline bf16x8 pack8(float4 a, float4 b){
  BF8 r; r.u[0] = pk2(a.x, a.y); r.u[1] = pk2(a.z, a.w);
  r.u[2] = pk2(b.x, b.y); r.u[3] = pk2(b.z, b.w); return r.v;
}

// stage 32KB (32 frags of 512 ushorts) of frag-ordered weights into LDS (fused load+write)
__device__ inline void stage_wf(const unsigned short* __restrict__ src,
                                unsigned short* dst, int tid){
#pragma unroll
  for (int i = 0; i < 4; ++i){
    int p = tid + i*TPM;
    *(uint4*)(dst + p*8) = *(const uint4*)(src + p*8);
  }
}

// 2 K-chunks (128 K) of MFMA for a 16x128 wave tile; B from LDS wbuf (frags 0..31)
__device__ inline void gemm_lds2(const bf16x8* a, const unsigned short* wbuf,
                                 f32x4 acc[8], int lane){
#pragma unroll
  for (int cl = 0; cl < 2; ++cl)
#pragma unroll
    for (int kk = 0; kk < 2; ++kk){
      bf16x8 av = a[cl*2 + kk];
#pragma unroll
      for (int n = 0; n < 8; ++n){
        bf16x8 bv = *(const bf16x8*)(wbuf + (size_t)(((cl*8 + n)*2 + kk)*512) + lane*8);
        acc[n] = __builtin_amdgcn_mfma_f32_16x16x32_bf16(av, bv, acc[n], 0, 0, 0);
      }
    }
}

// per-row LN stats, in-wave (rows = lg*4+ri, cols = n*16+il)
__device__ inline void rowstats(const f32x4 acc[8], const float bia[8],
                                float mean[4], float rstd[4]){
#pragma unroll
  for (int ri = 0; ri < 4; ++ri){
    float s = 0.f, q = 0.f;
#pragma unroll
    for (int n = 0; n < 8; ++n){
      float z = acc[n][ri] + bia[n];
      s += z; q += z*z;
    }
#pragma unroll
    for (int m = 1; m < 16; m <<= 1){ s += __shfl_xor(s, m); q += __shfl_xor(q, m); }
    mean[ri] = s * (1.f/128.f);
    float var = q * (1.f/128.f) - mean[ri]*mean[ri];
    rstd[ri] = rsqrtf(var + 1e-5f);
  }
}

// =======================  kernels  =======================

// CSR-binned segment mean (verified R3-R8)
__global__ __launch_bounds__(TPB) void k_pool(const float* __restrict__ fine,
                                              const int* __restrict__ idx,
                                              unsigned short* __restrict__ pooled){
  int b = blockIdx.x >> 6, g = blockIdx.x & 63;
  int c0 = g * 8;
  __shared__ int sidx[4096];
  __shared__ int rows[512];
  __shared__ int cnt[8], off[9], woff[8];
  int tid = threadIdx.x;
  const int* idx_b = idx + b*4096;
  for (int i = tid; i < 4096; i += TPB) sidx[i] = idx_b[i];
  if (tid < 8) cnt[tid] = 0;
  __syncthreads();
  for (int i = tid; i < 4096; i += TPB){
    unsigned d = (unsigned)(sidx[i] - c0);
    if (d < 8u) atomicAdd(&cnt[d], 1);
  }
  __syncthreads();
  if (tid == 0){
    int s = 0;
#pragma unroll
    for (int j = 0; j < 8; ++j){ off[j] = s; s += cnt[j]; }
    off[8] = s;
  }
  __syncthreads();
  if (tid < 8) woff[tid] = off[tid];
  __syncthreads();
  for (int i = tid; i < 4096; i += TPB){
    unsigned d = (unsigned)(sidx[i] - c0);
    if (d < 8u){ int p = atomicAdd(&woff[d], 1); if (p < 512) rows[p] = i; }
  }
  __syncthreads();
  int hw = tid >> 5, l32 = tid & 31;
  const float* fb = fine + (size_t)b*4096*128;
  int o0 = off[hw], o1 = off[hw+1];
  float4 s = {0.f, 0.f, 0.f, 0.f};
  for (int m = o0; m < o1; ++m){
    float4 v = *((const float4*)(fb + (size_t)rows[m]*128) + l32);
    s.x += v.x; s.y += v.y; s.z += v.z; s.w += v.w;
  }
  float inv = 1.f / fmaxf((float)(o1 - o0), 1.f);
  unsigned short* po = pooled + ((size_t)(b*512 + c0 + hw))*128 + l32*4;
  po[0] = f2bf(s.x*inv); po[1] = f2bf(s.y*inv);
  po[2] = f2bf(s.z*inv); po[3] = f2bf(s.w*inv);
}

// per-batch sum over N of global_features (scaled at use time) — separate kernel;
// fusing this as global atomics into k_mega cost ~180us of contended-atomic drain (R7/R8).
__global__ __launch_bounds__(TPB) void k_gmean(const float* __restrict__ glob,
                                               float* __restrict__ gmean){
  int b = blockIdx.x >> 5, s = blockIdx.x & 31;
  int tid = threadIdx.x;
  int h = tid & 127, half = tid >> 7;
  __shared__ float part[128];
  const float* gb = glob + ((size_t)b*4096 + s*128)*128;
  float acc = 0.f;
  for (int r = half; r < 128; r += 2) acc += gb[(size_t)r*128 + h];
  if (half) part[h] = acc;
  __syncthreads();
  if (!half) atomicAdd(&gmean[b*128 + h], acc + part[h]);
}

// W [K][128] fp32 -> B-fragment-ordered bf16 (frag=(c*8+nblk)*2+kk; 512 ushorts/frag)
__global__ __launch_bounds__(TPB) void k_prep(const float* __restrict__ Wp, const float* __restrict__ Wu,
                       const float* __restrict__ Wg, const float* __restrict__ Wgl,
                       unsigned short* __restrict__ WfP, unsigned short* __restrict__ WfU,
                       unsigned short* __restrict__ WfG, unsigned short* __restrict__ WfGl){
  int e = blockIdx.x * TPB + threadIdx.x;      // 0..32767
  int j = e & 7, lane = (e >> 3) & 63, frag = e >> 9;
  int kk = frag & 1, nblk = (frag >> 1) & 7, c = frag >> 4;
  int il = lane & 15, lg = lane >> 4;
  int col = nblk*16 + il;
  int k = c*64 + kk*32 + lg*8 + j;
  if (e < 16384){
    WfP[e] = f2bf(Wp[k*128 + col]);
    WfU[e] = f2bf(Wu[k*128 + col]);
  }
  WfG[e]  = f2bf(Wg[k*128 + col]);
  WfGl[e] = f2bf(Wgl[k*128 + col]);
}

// Fused pipeline: 8 waves/block, each wave an independent 16x128 tile (128 rows/block).
// Weights staged through a shared 32KB LDS window in 5 phases (R6 structure, tile doubled).
template<int PATH>   // 0 = fine path, 1 = coarse path
__global__ __launch_bounds__(TPM, 4) void k_mega(
    const float* __restrict__ a_src,
    const float* __restrict__ gath_src,
    const unsigned short* __restrict__ x1b,
    const int* __restrict__ idx,
    const float* __restrict__ gsrc,
    float gscale,
    const unsigned short* __restrict__ Wf1, const float* __restrict__ b1,
    const float* __restrict__ g1, const float* __restrict__ be1,
    const unsigned short* __restrict__ WfG, const float* __restrict__ bG,
    const unsigned short* __restrict__ WfGl, const float* __restrict__ bGl,
    const float* __restrict__ gGl, const float* __restrict__ beGl,
    float* __restrict__ out)
{
  __shared__ __align__(16) unsigned short wbuf[16384];      // 32 KB weight phase window
  __shared__ __align__(16) unsigned short ubuf[8][16*UPAD]; // 34.8 KB per-wave u scratch
  int tid = threadIdx.x;
  int wave = tid >> 6, lane = tid & 63;
  int il = lane & 15, lg = lane >> 4;
  int row0 = blockIdx.x * 128 + wave * 16;
  int b = (PATH == 0) ? (row0 >> 12) : (row0 >> 9);
  unsigned short* u = ubuf[wave];

  // ===== prologue: A1 loads + W1 stage =====
  bf16x8 a1[4];
  if (PATH == 0){
    int n0 = row0 & 4095;
    int ci = idx[b*4096 + n0 + il];
    bool valid = (unsigned)ci < 512u;
    const float* cr = gath_src + ((size_t)b*512 + (valid ? ci : 0))*128;
#pragma unroll
    for (int c = 0; c < 2; ++c)
#pragma unroll
      for (int kk = 0; kk < 2; ++kk){
        float4 f0 = {0.f,0.f,0.f,0.f}, f1 = {0.f,0.f,0.f,0.f};
        if (valid){
          f0 = *(const float4*)(cr + c*64 + kk*32 + lg*8);
          f1 = *(const float4*)(cr + c*64 + kk*32 + lg*8 + 4);
        }
        a1[c*2 + kk] = pack8(f0, f1);
      }
  } else {
    const unsigned short* pr = x1b + (size_t)(row0 + il)*128;
#pragma unroll
    for (int c = 0; c < 2; ++c)
#pragma unroll
      for (int kk = 0; kk < 2; ++kk)
        a1[c*2 + kk] = *(const bf16x8*)(pr + c*64 + kk*32 + lg*8);
  }
  stage_wf(Wf1, wbuf, tid);
  __syncthreads();                              // S1: W1 ready

  f32x4 acc[8] = {};
  gemm_lds2(a1, wbuf, acc, lane);
  {
    float bia[8], gmv[8], btv[8];
#pragma unroll
    for (int n = 0; n < 8; ++n){
      int col = n*16 + il;
      bia[n] = b1[col]; gmv[n] = g1[col]; btv[n] = be1[col];
    }
    float mean[4], rstd[4];
    rowstats(acc, bia, mean, rstd);
#pragma unroll
    for (int ri = 0; ri < 4; ++ri)
#pragma unroll
      for (int n = 0; n < 8; ++n){
        float z = acc[n][ri] + bia[n];
        float y = fmaxf((z - mean[ri])*rstd[ri]*gmv[n] + btv[n], 0.f);
        u[(lg*4 + ri)*UPAD + n*16 + il] = f2bf(y);
      }
  }

  // prefetch GEMM2 global-A (consumed 2 barriers later)
  const float* ar = a_src + (size_t)(row0 + il)*128;
  float4 raw[8];
#pragma unroll
  for (int c = 0; c < 2; ++c)
#pragma unroll
    for (int kk = 0; kk < 2; ++kk){
      raw[(c*2+kk)*2+0] = *(const float4*)(ar + c*64 + kk*32 + lg*8);
      raw[(c*2+kk)*2+1] = *(const float4*)(ar + c*64 + kk*32 + lg*8 + 4);
    }

  __syncthreads();                              // S2: all done reading W1
  stage_wf(WfG, wbuf, tid);                     // WG K 0-127
  __syncthreads();                              // S3: WG-lo ready

  // ===== GEMM2 (gate): chunks 0,1 from global A =====
#pragma unroll
  for (int n = 0; n < 8; ++n) acc[n] = (f32x4){0.f,0.f,0.f,0.f};
  bf16x8 af[4];
#pragma unroll
  for (int f = 0; f < 4; ++f) af[f] = pack8(raw[f*2], raw[f*2+1]);
  gemm_lds2(af, wbuf, acc, lane);

  __syncthreads();                              // S4: done reading WG-lo
  stage_wf(WfG + 16384, wbuf, tid);             // WG K 128-255
#pragma unroll
  for (int cl = 0; cl < 2; ++cl)                // u1 frags (per-wave scratch, no barrier)
#pragma unroll
    for (int kk = 0; kk < 2; ++kk)
      af[cl*2 + kk] = *(const bf16x8*)(u + il*UPAD + cl*64 + kk*32 + lg*8);
  __syncthreads();                              // S5: WG-hi ready
  gemm_lds2(af, wbuf, acc, lane);

  // gate epilogue: u2 = g*a + (1-g)*u1 (per-lane RMW on own u addrs)
#pragma unroll
  for (int ri = 0; ri < 4; ++ri){
    int grow = (row0 + lg*4 + ri)*128;
#pragma unroll
    for (int n = 0; n < 8; ++n){
      int col = n*16 + il;
      float z = acc[n][ri] + bG[col];
      float gt = 1.f / (1.f + __expf(-z));
      float f  = a_src[(size_t)grow + col];
      int ua = (lg*4 + ri)*UPAD + col;
      float u1 = bf2f(u[ua]);
      u[ua] = f2bf(gt*f + (1.f - gt)*u1);
    }
  }

  // prefetch GEMM3 global-A (glob rows | gmean broadcast)
  if (PATH == 0){
    const float* gr = gsrc + (size_t)(row0 + il)*128;
#pragma unroll
    for (int c = 0; c < 2; ++c)
#pragma unroll
      for (int kk = 0; kk < 2; ++kk){
        raw[(c*2+kk)*2+0] = *(const float4*)(gr + c*64 + kk*32 + lg*8);
        raw[(c*2+kk)*2+1] = *(const float4*)(gr + c*64 + kk*32 + lg*8 + 4);
      }
  } else {
    const float* gm = gsrc + b*128;
#pragma unroll
    for (int c = 0; c < 2; ++c)
#pragma unroll
      for (int kk = 0; kk < 2; ++kk){
        float4 f0 = *(const float4*)(gm + c*64 + kk*32 + lg*8);
        float4 f1 = *(const float4*)(gm + c*64 + kk*32 + lg*8 + 4);
        raw[(c*2+kk)*2+0] = (float4){f0.x*gscale, f0.y*gscale, f0.z*gscale, f0.w*gscale};
        raw[(c*2+kk)*2+1] = (float4){f1.x*gscale, f1.y*gscale, f1.z*gscale, f1.w*gscale};
      }
  }

  __syncthreads();                              // S6: done reading WG-hi
  stage_wf(WfGl, wbuf, tid);                    // WGl K 0-127 (u2 part)
#pragma unroll
  for (int cl = 0; cl < 2; ++cl)                // u2 frags (per-wave scratch)
#pragma unroll
    for (int kk = 0; kk < 2; ++kk)
      af[cl*2 + kk] = *(const bf16x8*)(u + il*UPAD + cl*64 + kk*32 + lg*8);
  __syncthreads();                              // S7: WGl-lo ready

  // ===== GEMM3 (glob): chunks 0,1 from u2 =====
#pragma unroll
  for (int n = 0; n < 8; ++n) acc[n] = (f32x4){0.f,0.f,0.f,0.f};
  gemm_lds2(af, wbuf, acc, lane);

  __syncthreads();                              // S8: done reading WGl-lo
  stage_wf(WfGl + 16384, wbuf, tid);            // WGl K 128-255
#pragma unroll
  for (int f = 0; f < 4; ++f) af[f] = pack8(raw[f*2], raw[f*2+1]);
  __syncthreads();                              // S9: ready
  gemm_lds2(af, wbuf, acc, lane);

  // final LN + residual
  {
    float bia[8], gmv[8], btv[8];
#pragma unroll
    for (int n = 0; n < 8; ++n){
      int col = n*16 + il;
      bia[n] = bGl[col]; gmv[n] = gGl[col]; btv[n] = beGl[col];
    }
    float mean[4], rstd[4];
    rowstats(acc, bia, mean, rstd);
#pragma unroll
    for (int ri = 0; ri < 4; ++ri){
      int grow = (row0 + lg*4 + ri)*128;
#pragma unroll
      for (int n = 0; n < 8; ++n){
        int col = n*16 + il;
        float z = acc[n][ri] + bia[n];
        float y = fmaxf((z - mean[ri])*rstd[ri]*gmv[n] + btv[n], 0.f);
        float u2 = bf2f(u[(lg*4 + ri)*UPAD + col]);
        out[(size_t)grow + col] = u2 + 0.1f*y;
      }
    }
  }
}

extern "C" void kernel_launch(void* const* d_in, const int* in_sizes, int n_in,
                              void* d_out, int out_size, void* d_ws, size_t ws_size,
                              hipStream_t stream){
  const float* fine    = (const float*)d_in[0];
  const float* coarse  = (const float*)d_in[1];
  const float* glob    = (const float*)d_in[2];
  const int*   idx     = (const int*)  d_in[3];
  const float* W_pool  = (const float*)d_in[4];
  const float* b_pool  = (const float*)d_in[5];
  const float* g_pool  = (const float*)d_in[6];
  const float* be_pool = (const float*)d_in[7];
  const float* W_unpool  = (const float*)d_in[8];
  const float* b_unpool  = (const float*)d_in[9];
  const float* g_unpool  = (const float*)d_in[10];
  const float* be_unpool = (const float*)d_in[11];
  const float* W_gate = (const float*)d_in[12];
  const float* b_gate = (const float*)d_in[13];
  const float* W_glob = (const float*)d_in[14];
  const float* b_glob = (const float*)d_in[15];
  const float* g_glob = (const float*)d_in[16];
  const float* be_glob= (const float*)d_in[17];

  const int B = 32, N = 4096, C = 512;
  float* out_fine   = (float*)d_out;
  float* out_coarse = out_fine + (size_t)B*N*128;

  char* w = (char*)d_ws;
  unsigned short* WfP  = (unsigned short*)w; w += 16384*2;
  unsigned short* WfU  = (unsigned short*)w; w += 16384*2;
  unsigned short* WfG  = (unsigned short*)w; w += 32768*2;
  unsigned short* WfGl = (unsigned short*)w; w += 32768*2;
  float* gmean = (float*)w;                  w += B*128*4;
  unsigned short* pooled = (unsigned short*)w; w += (size_t)B*C*128*2;

  hipMemsetAsync(gmean, 0, B*128*4, stream);
  k_prep<<<128, TPB, 0, stream>>>(W_pool, W_unpool, W_gate, W_glob, WfP, WfU, WfG, WfGl);
  k_pool<<<B*64, TPB, 0, stream>>>(fine, idx, pooled);
  k_gmean<<<B*32, TPB, 0, stream>>>(glob, gmean);

  // fine path: unpool(gather) -> gate -> glob
  k_mega<0><<<(B*N)/128, TPM, 0, stream>>>(fine, coarse, nullptr, idx, glob, 1.0f,
                                           WfU, b_unpool, g_unpool, be_unpool,
                                           WfG, b_gate, WfGl, b_glob, g_glob, be_glob,
                                           out_fine);
  // coarse path: pool-block -> gate -> glob
  k_mega<1><<<(B*C)/128, TPM, 0, stream>>>(coarse, nullptr, pooled, nullptr, gmean, 1.f/4096.f,
                                           WfP, b_pool, g_pool, be_pool,
                                           WfG, b_gate, WfGl, b_glob, g_glob, be_glob,
                                           out_coarse);
}